// Round 9
// baseline (143.370 us; speedup 1.0000x reference)
//
#include <hip/hip_runtime.h>

// InfoNCE loss:
//   loss = (1/B) * sum_i [ log(sum_j exp(Q_i . D_j / T)) - Q_i . D_{i*dp} / T ]
//
// R13 = 256x128 tile with 8 WAVES (512 thr, 4M x 2N), each wave an EXACT
// per-wave clone of R4's verified workload (4 A-frags, 4 B-frags, 16 MFMA
// 16x16x128, 16 acc frags = 64 AGPR).  R12 post-mortem: unified VGPR+AGPR
// file means per-thread total must stay <= 128 for 16 waves/CU; R12's
// 32-frag acc (236/thread) pinned it at 8 waves/CU and lost.  This keeps
// R4's 128/thread envelope while doubling waves/block:
//   - 2 blocks/CU x 8 waves = 16 waves/CU (vs R4's measured ~9.4) -> more
//     concurrent MFMA streams to cover each block's serial stage-drain.
//   - intensity BM*BN/(BM+BN) = 85 vs R4's 64 (x1.33 less staging/FLOP).
//   - same 2-barrier K-loop, 48KB single-buffer LDS, global_load_lds
//     staging (6 chunks/wave), R4 epilogue re-indexed.
//   - XCD swizzle (R7-verified): 1024 blocks = 8 XCDs x (8bx x 16by);
//     per-XCD slab 2MB A + 2MB B = one 4MB L2.
//   - __launch_bounds__(512, 2): empirical 128-reg/thread budget (R8) =
//     exactly this kernel's demand; no spill expected (R8-R11 spilled at
//     demand ~230).
//
// Tiled global layout (per matrix, unchanged): for 128-row block R, 128-wide
// k-block k0b: 16KB image = 16 chunks x 1KB. Chunk c = rg*2 + kh (rg=0..7
// 16-row group, kh=0..1 64-col half); slot l (16B) holds
//   X[R*128 + rg*16 + (l&15)][k0b*128 + kh*64 + (l>>4)*16 .. +16]   (fp8)
//
// ws layout (~12.1 MB):
//   [0)       Q8  B*K fp8     (4 MB)
//   [B*K)     D8  N*K fp8     (8 MB)
//   [+N*K)    rowsum B f32    (16 KB)  zeroed by cvt kernel
//   [+B*4)    pos    B f32    (16 KB)  written by gemm epilogue

#define TEMP_INV 50.0f
#define PRESCALE 16.0f
#define SCALE_BYTE 123   // e8m0: 2^(123-127) = 2^-4 per operand

typedef int   i32x4 __attribute__((ext_vector_type(4)));
typedef int   i32x8 __attribute__((ext_vector_type(8)));
typedef float f32x4 __attribute__((ext_vector_type(4)));

// ---------------- fp32 -> fp8 e4m3 (x16), pre-tiled; zero rowsum ----------
__global__ void cvt_kernel(const float* __restrict__ Q, const float* __restrict__ Dm,
                           unsigned int* __restrict__ Q8, unsigned int* __restrict__ D8,
                           float* __restrict__ rowsum, int qSlots, int B, int K) {
    const int gid = blockIdx.x * blockDim.x + threadIdx.x;
    if (gid < B) rowsum[gid] = 0.0f;
    const float* src;
    unsigned int* dst;
    int s;
    if (gid < qSlots) { src = Q;  dst = Q8; s = gid; }
    else              { src = Dm; dst = D8; s = gid - qSlots; }
    // Slot permutation within the 64-slot chunk (R7, kept): lane l handles
    // slot ((l&3)<<4)|(l>>2) -> reads coalesce to 256B runs.
    {
        const int l0 = s & 63;
        s = (s & ~63) | (((l0 & 3) << 4) | (l0 >> 2));
    }
    const int l   = s & 63;
    const int c   = (s >> 6) & 15;
    const int k0b = (s >> 10) & 7;
    const int R   = s >> 13;
    const int row = R * 128 + (c >> 1) * 16 + (l & 15);
    const int k   = k0b * 128 + (c & 1) * 64 + (l >> 4) * 16;
    const float* p = src + (size_t)row * K + k;
    unsigned int w[4];
#pragma unroll
    for (int d = 0; d < 4; ++d) {
        float4 v = *(const float4*)(p + d * 4);
        int t = __builtin_amdgcn_cvt_pk_fp8_f32(v.x * PRESCALE, v.y * PRESCALE, 0, false);
        t = __builtin_amdgcn_cvt_pk_fp8_f32(v.z * PRESCALE, v.w * PRESCALE, t, true);
        w[d] = (unsigned int)t;
    }
    *(uint4*)(dst + (size_t)s * 4) = make_uint4(w[0], w[1], w[2], w[3]);
}

// ---------------- fused MX-fp8 GEMM + row sum-exp + pos extraction --------
// grid: 1D 1024 blocks (XCD-swizzled -> bx in [0,16), by in [0,64)),
// 512 threads (8 waves, 4M x 2N), tile 256x128, BK=128, 48KB LDS,
// R4's verified 2-barrier loop; per-wave workload = R4 clone.
__global__ __launch_bounds__(512, 2) void gemm_expsum_kernel(
        const unsigned int* __restrict__ Q8, const unsigned int* __restrict__ D8,
        const int* __restrict__ dper,
        float* __restrict__ rowsum, float* __restrict__ pos, int K) {
    __shared__ unsigned int BUF[12288];   // 48KB: A 8192 dw (2 images) + B 4096 dw

    const int tid   = threadIdx.x;
    const int wave  = tid >> 6;
    const int lane  = tid & 63;
    const int wr    = wave >> 1;         // 0..3 -> 64-row strip of 256 rows
    const int wc    = wave & 1;          // 0..1 -> 64-col half of 128 cols
    const int lquad = lane >> 4;
    const int lm    = lane & 15;
    const int kh    = lquad >> 1;        // 64-col k-half for fragment reads

    // XCD-aware bijective swizzle: 1024 = 8 XCDs x (8bx x 16by) sub-tiles.
    const int f   = blockIdx.x;
    const int xcd = f & 7;
    const int sub = f >> 3;              // 0..127
    const int bx  = (xcd & 1) * 8 + (sub & 7);     // 0..15
    const int by  = (xcd >> 1) * 16 + (sub >> 3);  // 0..63

    const int qbase = bx * 256;
    const int dbase = by * 128;
    const int KB    = K >> 7;            // 8 k-blocks

    // ---- fragment LDS dword offsets ----
    // A frag i (i=0..3): 16-row group ra = wr*4+i; chunk (ra>>3)*16+(ra&7)*2+kh
    //   with ra>>3 = wr>>1, ra&7 = (wr&1)*4+i  ->  base + i*512.
    // B frag j (j=0..3): col group gb = wc*4+j; chunk 32+gb*2+kh -> 8192+...
    const int slotofs = ((lquad & 1) * 32 + lm) * 4;   // lo slot; hi adds 64
    const int aofs = ((wr >> 1) * 16 + (wr & 1) * 8 + kh) * 256 + slotofs;
    const int bofs = 8192 + (wc * 8 + kh) * 256 + slotofs;

    f32x4 acc[16];
#pragma unroll
    for (int t = 0; t < 16; ++t) acc[t] = (f32x4){0.f, 0.f, 0.f, 0.f};

#define LDFRAG(dst_, off_) do {                                              \
        i32x4 lo_ = *(const i32x4*)(BUF + (off_));                           \
        i32x4 hi_ = *(const i32x4*)(BUF + (off_) + 64);                      \
        dst_ = __builtin_shufflevector(lo_, hi_, 0, 1, 2, 3, 4, 5, 6, 7);    \
    } while (0)

#define MFMA1(AA, BB, IDX)                                                   \
        acc[IDX] = __builtin_amdgcn_mfma_scale_f32_16x16x128_f8f6f4(         \
            AA, BB, acc[IDX], 0, 0, 0, SCALE_BYTE, 0, SCALE_BYTE)

    for (int kb = 0; kb < KB; ++kb) {
        // ---- stage: 6 chunks per wave (48 total: 32 A + 16 B), lane-linear ----
#pragma unroll
        for (int q = 0; q < 6; ++q) {
            const int fl = wave * 6 + q;             // 0..47
            const unsigned int* g;
            if (fl < 32)
                g = Q8 + (size_t)(2 * bx + (fl >> 4)) * (KB * 4096)
                       + kb * 4096 + (fl & 15) * 256 + lane * 4;
            else
                g = D8 + (size_t)by * (KB * 4096)
                       + kb * 4096 + (fl - 32) * 256 + lane * 4;
            __builtin_amdgcn_global_load_lds(
                (const __attribute__((address_space(1))) void*)g,
                (__attribute__((address_space(3))) void*)(BUF + fl * 256 + lane * 4),
                16, 0, 0);
        }
        __syncthreads();   // drains vmcnt -> LDS tile ready

        i32x8 B0, B1, B2, B3, A0, A1, A2, A3;
        LDFRAG(B0, bofs + 0 * 512);
        LDFRAG(B1, bofs + 1 * 512);
        LDFRAG(B2, bofs + 2 * 512);
        LDFRAG(B3, bofs + 3 * 512);
        LDFRAG(A0, aofs + 0 * 512);
        LDFRAG(A1, aofs + 1 * 512);
        LDFRAG(A2, aofs + 2 * 512);
        LDFRAG(A3, aofs + 3 * 512);
        MFMA1(A0, B0,  0); MFMA1(A0, B1,  1); MFMA1(A0, B2,  2); MFMA1(A0, B3,  3);
        MFMA1(A1, B0,  4); MFMA1(A1, B1,  5); MFMA1(A1, B2,  6); MFMA1(A1, B3,  7);
        MFMA1(A2, B0,  8); MFMA1(A2, B1,  9); MFMA1(A2, B2, 10); MFMA1(A2, B3, 11);
        MFMA1(A3, B0, 12); MFMA1(A3, B1, 13); MFMA1(A3, B2, 14); MFMA1(A3, B3, 15);
        __syncthreads();   // all waves done reading before next stage
    }
#undef MFMA1
#undef LDFRAG

    // ---- epilogue. 16x16 C layout: col = lane&15, row = (lane>>4)*4+reg ----
    const int dp = dper[0];
#pragma unroll
    for (int i = 0; i < 4; ++i)
#pragma unroll
        for (int r = 0; r < 4; ++r) {
            const int gr   = qbase + wr * 64 + 16 * i + 4 * lquad + r;
            const int pcol = gr * dp - dbase;   // local col of positive, if here
            float e = 0.0f;
#pragma unroll
            for (int j = 0; j < 4; ++j) {
                float v = acc[i * 4 + j][r];
                if (wc * 64 + 16 * j + lm == pcol) pos[gr] = v * TEMP_INV;
                e += __expf(v * TEMP_INV);
            }
            e += __shfl_xor(e, 1);
            e += __shfl_xor(e, 2);
            e += __shfl_xor(e, 4);
            e += __shfl_xor(e, 8);
            if (lm == 0) atomicAdd(&rowsum[gr], e);
        }
}

// ---------------- final: loss = sum(log(rowsum) - pos)/B ----------------
__global__ void final_kernel(const float* __restrict__ rowsum,
                             const float* __restrict__ pos,
                             float* __restrict__ out, int B) {
    __shared__ float red[16];
    int tid = threadIdx.x;   // 1024 threads
    float s = 0.0f;
    for (int i = tid; i < B; i += blockDim.x)
        s += __logf(rowsum[i]) - pos[i];
    s += __shfl_xor(s, 32);
    s += __shfl_xor(s, 16);
    s += __shfl_xor(s, 8);
    s += __shfl_xor(s, 4);
    s += __shfl_xor(s, 2);
    s += __shfl_xor(s, 1);
    int w = tid >> 6, l = tid & 63;
    if (l == 0) red[w] = s;
    __syncthreads();
    if (tid == 0) {
        float t = 0.0f;
        int nw = blockDim.x >> 6;
        for (int i = 0; i < nw; ++i) t += red[i];
        out[0] = t / (float)B;
    }
}

extern "C" void kernel_launch(void* const* d_in, const int* in_sizes, int n_in,
                              void* d_out, int out_size, void* d_ws, size_t ws_size,
                              hipStream_t stream) {
    const float* Q   = (const float*)d_in[0];
    const float* Dm  = (const float*)d_in[1];
    const int* dper  = (const int*)d_in[2];
    float* out = (float*)d_out;

    const int DIM  = 1024;
    const int B    = in_sizes[0] / DIM;   // 4096
    const int Ntot = in_sizes[1] / DIM;   // 8192

    unsigned int* Q8 = (unsigned int*)d_ws;
    unsigned int* D8 = Q8 + (size_t)B * DIM / 4;
    float* rowsum = (float*)(D8 + (size_t)Ntot * DIM / 4);
    float* pos = rowsum + B;

    const int qSlots = B * DIM / 16;            // 262144
    const int dSlots = Ntot * DIM / 16;         // 524288
    cvt_kernel<<<(qSlots + dSlots) / 256, 256, 0, stream>>>(
        Q, Dm, Q8, D8, rowsum, qSlots, B, DIM);

    const int nblk = (B / 256) * (Ntot / 128);  // 1024 = 8 * 128
    gemm_expsum_kernel<<<nblk, 512, 0, stream>>>(Q8, D8, dper, rowsum, pos, DIM);

    final_kernel<<<1, 1024, 0, stream>>>(rowsum, pos, out, B);
}

// Round 10
// 128.727 us; speedup vs baseline: 1.1138x; 1.1138x over previous
//
#include <hip/hip_runtime.h>

// InfoNCE loss:
//   loss = (1/B) * sum_i [ log(sum_j exp(Q_i . D_j / T)) - Q_i . D_{i*dp} / T ]
//
// R14 = REVERT to R7, the best harness-verified kernel (128.75us total,
// gemm 45.2us = 1521 TF = 93% of the m97-structure fp8-MX ceiling).
//
// Why this is terminal (constraint map from R5-R13):
//  - gemm is NOT memory-bound: R7's XCD swizzle halved FETCH (35->16.4MB)
//    with zero time change. The cost is the per-K-step stage-drain convoy,
//    hidden only by ~2.3 resident blocks' cross-block MFMA overlap.
//  - The documented escape (8-phase 256^2, needs >128 regs/thread at >=8
//    waves/block) is unreachable on this toolchain:
//      * 512/1024-thread blocks are register-budgeted to ~128/64 per thread
//        and SPILL acc (R8/R9/R11: WRITE_SIZE 647-887MB scratch), invariant
//        under __launch_bounds__ variants;
//      * 8-wave blocks at ~148 regs/thread drop to 1 block/CU by block
//        granularity (R13: occupancy 6.7 waves/CU, 64.4us);
//      * fat-tile 4-wave variants (R12: 236 regs/thread) pin at 8 waves/CU
//        and lose the cross-block overlap (51.3us).
//  - Within the viable envelope (256 thr, <=128 regs/thread incl AGPR),
//    schedule variants measured 45-65us; R7's 2-barrier loop is the best
//    and sits at 93% of that structure's documented ceiling.
//  - Remaining dur_us budget is fixed: ~46us harness 256MiB workspace fill,
//    ~12us cvt, ~6us final, launch overhead.
//
//  1. GEMM grid: 1D (2048 blocks) with bijective XCD-aware swizzle.
//     f%8 = XCD (HW round-robin); each XCD gets a 16x16 sub-tile of the
//     (32 bx x 64 by) block grid -> per-XCD working set = 2MB Q + 2MB D
//     = one 4MB XCD L2 (verified: FETCH halved).
//  2. cvt: within each 64-slot (1KB) output chunk, lane l handles slot
//     ((l&3)<<4)|(l>>2) -> reads coalesce to 256B runs per row.
//
// Tiled global layout (per matrix): for 128-row block R, 128-wide k-block
// k0b: 16KB image = 16 chunks x 1KB. Chunk c = rg*2 + kh (rg=0..7 16-row
// group, kh=0..1 64-col half); slot l (16B) holds
//   X[R*128 + rg*16 + (l&15)][k0b*128 + kh*64 + (l>>4)*16 .. +16]   (fp8)
//
// ws layout (~12.1 MB):
//   [0)       Q8  B*K fp8     (4 MB)
//   [B*K)     D8  N*K fp8     (8 MB)
//   [+N*K)    rowsum B f32    (16 KB)  zeroed by cvt kernel
//   [+B*4)    pos    B f32    (16 KB)  written by gemm epilogue

#define TEMP_INV 50.0f
#define PRESCALE 16.0f
#define SCALE_BYTE 123   // e8m0: 2^(123-127) = 2^-4 per operand

typedef int   i32x4 __attribute__((ext_vector_type(4)));
typedef int   i32x8 __attribute__((ext_vector_type(8)));
typedef float f32x4 __attribute__((ext_vector_type(4)));

// ---------------- fp32 -> fp8 e4m3 (x16), pre-tiled; zero rowsum ----------
__global__ void cvt_kernel(const float* __restrict__ Q, const float* __restrict__ Dm,
                           unsigned int* __restrict__ Q8, unsigned int* __restrict__ D8,
                           float* __restrict__ rowsum, int qSlots, int B, int K) {
    const int gid = blockIdx.x * blockDim.x + threadIdx.x;
    if (gid < B) rowsum[gid] = 0.0f;
    const float* src;
    unsigned int* dst;
    int s;
    if (gid < qSlots) { src = Q;  dst = Q8; s = gid; }
    else              { src = Dm; dst = D8; s = gid - qSlots; }
    // Slot permutation within the 64-slot chunk: lane l handles slot
    // ((l&3)<<4)|(l>>2).  Reads coalesce to 256B runs; the wave still
    // writes the same contiguous 1KB chunk.
    {
        const int l0 = s & 63;
        s = (s & ~63) | (((l0 & 3) << 4) | (l0 >> 2));
    }
    const int l   = s & 63;
    const int c   = (s >> 6) & 15;
    const int k0b = (s >> 10) & 7;
    const int R   = s >> 13;
    const int row = R * 128 + (c >> 1) * 16 + (l & 15);
    const int k   = k0b * 128 + (c & 1) * 64 + (l >> 4) * 16;
    const float* p = src + (size_t)row * K + k;
    unsigned int w[4];
#pragma unroll
    for (int d = 0; d < 4; ++d) {
        float4 v = *(const float4*)(p + d * 4);
        int t = __builtin_amdgcn_cvt_pk_fp8_f32(v.x * PRESCALE, v.y * PRESCALE, 0, false);
        t = __builtin_amdgcn_cvt_pk_fp8_f32(v.z * PRESCALE, v.w * PRESCALE, t, true);
        w[d] = (unsigned int)t;
    }
    *(uint4*)(dst + (size_t)s * 4) = make_uint4(w[0], w[1], w[2], w[3]);
}

// ---------------- fused MX-fp8 GEMM + row sum-exp + pos extraction --------
// grid: 1D 2048 blocks (XCD-swizzled -> bx in [0,32), by in [0,64)),
// 256 threads (4 waves, 2x2 wave grid), BK=128. Verified 2-barrier loop.
__global__ __launch_bounds__(256, 2) void gemm_expsum_kernel(
        const unsigned int* __restrict__ Q8, const unsigned int* __restrict__ D8,
        const int* __restrict__ dper,
        float* __restrict__ rowsum, float* __restrict__ pos, int K) {
    __shared__ unsigned int Qs[4096];   // 16KB fragment-order image
    __shared__ unsigned int Ds[4096];

    const int tid   = threadIdx.x;
    const int wave  = tid >> 6;
    const int lane  = tid & 63;
    const int lquad = lane >> 4;
    const int lm    = lane & 15;

    // XCD-aware bijective swizzle: 2048 = 8 XCDs x (16 bx x 16 by) sub-tiles.
    const int f   = blockIdx.x;
    const int xcd = f & 7;
    const int sub = f >> 3;
    const int bx  = (xcd & 1) * 16 + (sub & 15);
    const int by  = (xcd >> 1) * 16 + (sub >> 4);

    const int qbase = bx * 128;
    const int dbase = by * 128;
    const int KB    = K >> 7;           // 8 k-blocks

    // fragment-read dword offsets: chunk(rg, kh=lquad>>1)*256 + slot*4,
    // slot = ((lquad&1)*2 + t)*16 + lm
    const int slotofs = ((lquad & 1) * 32 + lm) * 4;   // t=0; t=1 adds 64
    const int aofs = ((wave >> 1) * 8 + (lquad >> 1)) * 256 + slotofs;
    const int bofs = ((wave & 1) * 8 + (lquad >> 1)) * 256 + slotofs;

    const unsigned int* Qg = Q8 + (size_t)bx * KB * 4096;
    const unsigned int* Dg = D8 + (size_t)by * KB * 4096;

    f32x4 acc[16];
#pragma unroll
    for (int t = 0; t < 16; ++t) acc[t] = (f32x4){0.f, 0.f, 0.f, 0.f};

    for (int kb = 0; kb < KB; ++kb) {
#pragma unroll
        for (int q = 0; q < 4; ++q) {
            const int c = wave * 4 + q;
            const unsigned int* g1 = Qg + kb * 4096 + c * 256 + lane * 4;
            __builtin_amdgcn_global_load_lds(
                (const __attribute__((address_space(1))) void*)g1,
                (__attribute__((address_space(3))) void*)(Qs + c * 256 + lane * 4),
                16, 0, 0);
            const unsigned int* g2 = Dg + kb * 4096 + c * 256 + lane * 4;
            __builtin_amdgcn_global_load_lds(
                (const __attribute__((address_space(1))) void*)g2,
                (__attribute__((address_space(3))) void*)(Ds + c * 256 + lane * 4),
                16, 0, 0);
        }
        __syncthreads();   // drains vmcnt -> LDS tiles ready

        i32x8 a8[4], b8[4];
#pragma unroll
        for (int i = 0; i < 4; ++i) {
            i32x4 lo = *(const i32x4*)(Qs + aofs + i * 512);
            i32x4 hi = *(const i32x4*)(Qs + aofs + i * 512 + 64);
            a8[i] = __builtin_shufflevector(lo, hi, 0, 1, 2, 3, 4, 5, 6, 7);
        }
#pragma unroll
        for (int j = 0; j < 4; ++j) {
            i32x4 lo = *(const i32x4*)(Ds + bofs + j * 512);
            i32x4 hi = *(const i32x4*)(Ds + bofs + j * 512 + 64);
            b8[j] = __builtin_shufflevector(lo, hi, 0, 1, 2, 3, 4, 5, 6, 7);
        }
#pragma unroll
        for (int i = 0; i < 4; ++i)
#pragma unroll
            for (int j = 0; j < 4; ++j)
                acc[i * 4 + j] = __builtin_amdgcn_mfma_scale_f32_16x16x128_f8f6f4(
                    a8[i], b8[j], acc[i * 4 + j], 0, 0, 0, SCALE_BYTE, 0, SCALE_BYTE);
        __syncthreads();   // all waves done reading before next stage
    }

    // epilogue (verified). C layout: col = lane&15, row = (lane>>4)*4 + reg
    const int dp = dper[0];
#pragma unroll
    for (int i = 0; i < 4; ++i)
#pragma unroll
        for (int r = 0; r < 4; ++r) {
            const int gr   = qbase + (wave >> 1) * 64 + 16 * i + 4 * lquad + r;
            const int pcol = gr * dp - dbase;   // local col of positive, if here
            float e = 0.0f;
#pragma unroll
            for (int j = 0; j < 4; ++j) {
                float v = acc[i * 4 + j][r];
                if ((wave & 1) * 64 + 16 * j + lm == pcol) pos[gr] = v * TEMP_INV;
                e += __expf(v * TEMP_INV);
            }
            e += __shfl_xor(e, 1);
            e += __shfl_xor(e, 2);
            e += __shfl_xor(e, 4);
            e += __shfl_xor(e, 8);
            if (lm == 0) atomicAdd(&rowsum[gr], e);
        }
}

// ---------------- final: loss = sum(log(rowsum) - pos)/B ----------------
__global__ void final_kernel(const float* __restrict__ rowsum,
                             const float* __restrict__ pos,
                             float* __restrict__ out, int B) {
    __shared__ float red[16];
    int tid = threadIdx.x;   // 1024 threads
    float s = 0.0f;
    for (int i = tid; i < B; i += blockDim.x)
        s += __logf(rowsum[i]) - pos[i];
    s += __shfl_xor(s, 32);
    s += __shfl_xor(s, 16);
    s += __shfl_xor(s, 8);
    s += __shfl_xor(s, 4);
    s += __shfl_xor(s, 2);
    s += __shfl_xor(s, 1);
    int w = tid >> 6, l = tid & 63;
    if (l == 0) red[w] = s;
    __syncthreads();
    if (tid == 0) {
        float t = 0.0f;
        int nw = blockDim.x >> 6;
        for (int i = 0; i < nw; ++i) t += red[i];
        out[0] = t / (float)B;
    }
}

extern "C" void kernel_launch(void* const* d_in, const int* in_sizes, int n_in,
                              void* d_out, int out_size, void* d_ws, size_t ws_size,
                              hipStream_t stream) {
    const float* Q   = (const float*)d_in[0];
    const float* Dm  = (const float*)d_in[1];
    const int* dper  = (const int*)d_in[2];
    float* out = (float*)d_out;

    const int DIM  = 1024;
    const int B    = in_sizes[0] / DIM;   // 4096
    const int Ntot = in_sizes[1] / DIM;   // 8192

    unsigned int* Q8 = (unsigned int*)d_ws;
    unsigned int* D8 = Q8 + (size_t)B * DIM / 4;
    float* rowsum = (float*)(D8 + (size_t)Ntot * DIM / 4);
    float* pos = rowsum + B;

    const int qSlots = B * DIM / 16;            // 262144
    const int dSlots = Ntot * DIM / 16;         // 524288
    cvt_kernel<<<(qSlots + dSlots) / 256, 256, 0, stream>>>(
        Q, Dm, Q8, D8, rowsum, qSlots, B, DIM);

    const int nblk = (B / 128) * (Ntot / 128);  // 2048 = 8 * 256
    gemm_expsum_kernel<<<nblk, 256, 0, stream>>>(Q8, D8, dper, rowsum, pos, DIM);

    final_kernel<<<1, 1024, 0, stream>>>(rowsum, pos, out, B);
}